// Round 6
// baseline (170.089 us; speedup 1.0000x reference)
//
#include <hip/hip_runtime.h>
#include <hip/hip_bf16.h>

#define N_NODES 10000
#define N_EDGES 640000
#define CH 128
#define KN 118   // node_feat inner dim

typedef _Float16 h2 __attribute__((ext_vector_type(2)));
typedef _Float16 h8 __attribute__((ext_vector_type(8)));

#define H2_OF(v, k) __builtin_shufflevector((v), (v), 2 * (k), 2 * (k) + 1)

// K1: fold weights. M[mat][i][c] = sum_j Wn[i][j] * Wa1[mat*128 + j][c]
//     V[mat][c]    = sum_j bn[j]  * Wa1[mat*128 + j][c]  (+ ba1[c] for mat==1)
// Extra block (mat==2): convert w2 -> f16 table for k3.
__global__ __launch_bounds__(128) void k1_weights(
    const float* __restrict__ Wn, const float* __restrict__ bn,
    const float* __restrict__ Wa1, const float* __restrict__ ba1,
    const float* __restrict__ w2, float* __restrict__ M,
    float* __restrict__ V, _Float16* __restrict__ w2h) {
  int c = threadIdx.x;                 // 0..127
  int mat = blockIdx.x / 119;          // 0: src-half, 1: dst-half, 2: w2 conv
  int i = blockIdx.x % 119;            // 0..117 weight rows, 118 = bias row
  if (mat == 2) {
    w2h[c] = (_Float16)w2[c];
    return;
  }
  const float* B = Wa1 + mat * CH * CH;
  const float* a = (i < KN) ? (Wn + i * CH) : bn;
  float acc = 0.f;
#pragma unroll 8
  for (int j = 0; j < CH; ++j) acc = fmaf(a[j], B[j * CH + c], acc);
  if (i < KN) {
    M[(mat * KN + i) * CH + c] = acc;
  } else {
    if (mat == 1) acc += ba1[c];
    V[mat * CH + c] = acc;
  }
}

// K2: per-node tables, channel-SPLIT layout for k3's L2 residency:
//   T[half][mat][node][cc] = f16( nf[node][:] . M[mat][:][half*64+cc] + V )
// block = 256: c = tx&127, mat = tx>>7; 16 nodes per block. nf loads are
// block-uniform -> scalar unit; M loads and T stores coalesced per wave.
__global__ __launch_bounds__(256) void k2_nodes(
    const float* __restrict__ nf, const float* __restrict__ M,
    const float* __restrict__ V, _Float16* __restrict__ T) {
  int tx = threadIdx.x;
  int c = tx & (CH - 1);
  int mat = tx >> 7;
  int n0 = blockIdx.x * 16;
  const float* Mm = M + mat * KN * CH + c;
  const float* r = nf + (size_t)n0 * KN;
  float acc[16];
#pragma unroll
  for (int j = 0; j < 16; ++j) acc[j] = 0.f;
#pragma unroll 2
  for (int k = 0; k < KN; ++k) {
    float m = Mm[k * CH];
#pragma unroll
    for (int j = 0; j < 16; ++j) acc[j] = fmaf(r[j * KN + k], m, acc[j]);
  }
  float v = V[mat * CH + c];
  int half = c >> 6;
  int cc = c & 63;
  _Float16* t = T + ((size_t)half * 2 + mat) * N_NODES * 64 + cc;
#pragma unroll
  for (int j = 0; j < 16; ++j)
    t[(size_t)(n0 + j) * 64] = (_Float16)(acc[j] + v);
}

// lrelu(s+d) . w over 8 channels, f32 accumulate via v_dot2_f32_f16
__device__ inline float edge_acc8(h8 s, h8 d, h8 w) {
  h8 t = s + d;                                  // 4x v_pk_add_f16
  h8 p = t * (_Float16)0.01f;                    // 4x v_pk_mul_f16
  h8 u = __builtin_elementwise_max(t, p);        // 4x v_pk_max_f16 (leaky relu)
  float acc = 0.f;
  acc = __builtin_amdgcn_fdot2(H2_OF(u, 0), H2_OF(w, 0), acc, false);
  acc = __builtin_amdgcn_fdot2(H2_OF(u, 1), H2_OF(w, 1), acc, false);
  acc = __builtin_amdgcn_fdot2(H2_OF(u, 2), H2_OF(w, 2), acc, false);
  acc = __builtin_amdgcn_fdot2(H2_OF(u, 3), H2_OF(w, 3), acc, false);
  return acc;
}

// K3 (one channel-half per launch): partial[e] or out[e] =
//   sum_{cc<64} w2[cc] * lrelu(Sh[src[e]][cc] + Dh[dst[e]][cc])  (+partial+b2)
// Working set per pass = 2.56 MB < 4 MiB/XCD L2 -> gathers stay L2-resident.
// 8 lanes per edge-quad slot, 8 channels/lane, 4 edges/thread (8 gathers in
// flight, ~60 VGPR -> 8 waves/SIMD). Packed butterfly over 8 lanes.
__global__ __launch_bounds__(256) void k3_half(
    const int* __restrict__ src, const int* __restrict__ dst,
    const _Float16* __restrict__ Sh, const _Float16* __restrict__ Dh,
    const _Float16* __restrict__ w2h, const float* __restrict__ partial,
    const float* __restrict__ b2, float* __restrict__ outp, int fin) {
  int tid = blockIdx.x * 256 + threadIdx.x;
  int g = tid >> 3;             // edge-quad id, 0..N_EDGES/4-1
  int sub = tid & 7;
  int c0 = sub << 3;            // 8 channels (within this half) per lane

  h8 w = *(const h8*)(w2h + c0);
  int4 s4 = *(const int4*)(src + 4 * g);   // broadcast across the 8 lanes
  int4 d4 = *(const int4*)(dst + 4 * g);

  const _Float16* Sp = Sh + c0;
  const _Float16* Dp = Dh + c0;
  h8 s0 = *(const h8*)(Sp + ((size_t)s4.x << 6));
  h8 d0 = *(const h8*)(Dp + ((size_t)d4.x << 6));
  h8 s1 = *(const h8*)(Sp + ((size_t)s4.y << 6));
  h8 d1 = *(const h8*)(Dp + ((size_t)d4.y << 6));
  h8 s2 = *(const h8*)(Sp + ((size_t)s4.z << 6));
  h8 d2 = *(const h8*)(Dp + ((size_t)d4.z << 6));
  h8 s3 = *(const h8*)(Sp + ((size_t)s4.w << 6));
  h8 d3 = *(const h8*)(Dp + ((size_t)d4.w << 6));

  float a0 = edge_acc8(s0, d0, w);
  float a1 = edge_acc8(s1, d1, w);
  float a2 = edge_acc8(s2, d2, w);
  float a3 = edge_acc8(s3, d3, w);

  // packed butterfly: lane (sub&3)==k ends with the 8-lane sum for edge k
  float r0 = a0 + __shfl_xor(a0, 1);
  float r1 = a1 + __shfl_xor(a1, 1);
  float r2 = a2 + __shfl_xor(a2, 1);
  float r3 = a3 + __shfl_xor(a3, 1);
  float v0 = (sub & 1) ? r1 : r0;
  float v1 = (sub & 1) ? r3 : r2;
  float t0 = v0 + __shfl_xor(v0, 2);
  float t1 = v1 + __shfl_xor(v1, 2);
  float u = (sub & 2) ? t1 : t0;
  u += __shfl_xor(u, 4);

  if (sub < 4) {
    int e = 4 * g + sub;
    if (fin) u += partial[e] + b2[0];
    outp[e] = u;
  }
}

extern "C" void kernel_launch(void* const* d_in, const int* in_sizes, int n_in,
                              void* d_out, int out_size, void* d_ws, size_t ws_size,
                              hipStream_t stream) {
  const float* nf  = (const float*)d_in[0];
  // d_in[1] edge_feat, d_in[6] W_edge, d_in[7] b_edge: unused by the output
  const int*   src = (const int*)d_in[2];
  const int*   dst = (const int*)d_in[3];
  const float* Wn  = (const float*)d_in[4];
  const float* bn  = (const float*)d_in[5];
  const float* Wa1 = (const float*)d_in[8];
  const float* ba1 = (const float*)d_in[9];
  const float* Wa2 = (const float*)d_in[10];
  const float* ba2 = (const float*)d_in[11];
  float* out = (float*)d_out;

  char* ws = (char*)d_ws;
  float* M = (float*)ws;                                   // [2][118][128] f32
  float* V = (float*)(ws + 2 * KN * CH * sizeof(float));   // [2][128] f32
  _Float16* w2h = (_Float16*)(ws + (2 * KN * CH + 2 * CH) * sizeof(float));
  _Float16* T = (_Float16*)((char*)w2h + CH * sizeof(_Float16));
  // T layout: [half][mat][node][64] f16 -> each half is 2.56 MB
  _Float16* S0 = T;
  _Float16* D0 = T + (size_t)N_NODES * 64;
  _Float16* S1 = T + (size_t)2 * N_NODES * 64;
  _Float16* D1 = T + (size_t)3 * N_NODES * 64;
  float* P = (float*)(T + (size_t)4 * N_NODES * 64);       // [640000] f32 partial

  k1_weights<<<239, 128, 0, stream>>>(Wn, bn, Wa1, ba1, Wa2, M, V, w2h);
  k2_nodes<<<N_NODES / 16, 256, 0, stream>>>(nf, M, V, T);
  const int k3_blocks = (N_EDGES / 4 * 8) / 256;           // 5000
  k3_half<<<k3_blocks, 256, 0, stream>>>(src, dst, S0, D0, w2h, P, ba2, P, 0);
  k3_half<<<k3_blocks, 256, 0, stream>>>(src, dst, S1, D1, w2h + 64, P, ba2, out, 1);
}

// Round 7
// 166.877 us; speedup vs baseline: 1.0192x; 1.0192x over previous
//
#include <hip/hip_runtime.h>
#include <hip/hip_bf16.h>

#define N_NODES 10000
#define N_EDGES 640000
#define CH 128
#define KN 118   // node_feat inner dim

typedef _Float16 h2 __attribute__((ext_vector_type(2)));
typedef _Float16 h8 __attribute__((ext_vector_type(8)));

#define H2_OF(v, k) __builtin_shufflevector((v), (v), 2 * (k), 2 * (k) + 1)

// K1: fold weights. M[mat][i][c] = sum_j Wn[i][j] * Wa1[mat*128 + j][c]
//     V[mat][c]    = sum_j bn[j]  * Wa1[mat*128 + j][c]  (+ ba1[c] for mat==1)
// Extra block (mat==2): convert w2 -> f16 table for k3.
__global__ __launch_bounds__(128) void k1_weights(
    const float* __restrict__ Wn, const float* __restrict__ bn,
    const float* __restrict__ Wa1, const float* __restrict__ ba1,
    const float* __restrict__ w2, float* __restrict__ M,
    float* __restrict__ V, _Float16* __restrict__ w2h) {
  int c = threadIdx.x;                 // 0..127
  int mat = blockIdx.x / 119;          // 0: src-half, 1: dst-half, 2: w2 conv
  int i = blockIdx.x % 119;            // 0..117 weight rows, 118 = bias row
  if (mat == 2) {
    w2h[c] = (_Float16)w2[c];
    return;
  }
  const float* B = Wa1 + mat * CH * CH;
  const float* a = (i < KN) ? (Wn + i * CH) : bn;
  float acc = 0.f;
#pragma unroll 8
  for (int j = 0; j < CH; ++j) acc = fmaf(a[j], B[j * CH + c], acc);
  if (i < KN) {
    M[(mat * KN + i) * CH + c] = acc;
  } else {
    if (mat == 1) acc += ba1[c];
    V[mat * CH + c] = acc;
  }
}

// K2: per-node tables T[mat][n][c] = f16( nf[n][:] . M[mat][:][c] + V[mat][c] )
// block = 256: c = tx&127, mat = tx>>7; 16 nodes per block (halves the
// per-block M re-read stream vs 8/block: 150 MB -> 75 MB of L2 traffic).
// nf loads are block-uniform -> scalar unit; M loads coalesced.
__global__ __launch_bounds__(256) void k2_nodes(
    const float* __restrict__ nf, const float* __restrict__ M,
    const float* __restrict__ V, _Float16* __restrict__ T) {
  int tx = threadIdx.x;
  int c = tx & (CH - 1);
  int mat = tx >> 7;
  int n0 = blockIdx.x * 16;
  const float* Mm = M + mat * KN * CH + c;
  const float* r = nf + (size_t)n0 * KN;
  float acc[16];
#pragma unroll
  for (int j = 0; j < 16; ++j) acc[j] = 0.f;
#pragma unroll 2
  for (int k = 0; k < KN; ++k) {
    float m = Mm[k * CH];
#pragma unroll
    for (int j = 0; j < 16; ++j) acc[j] = fmaf(r[j * KN + k], m, acc[j]);
  }
  float v = V[mat * CH + c];
  _Float16* t = T + (size_t)mat * N_NODES * CH + c;
#pragma unroll
  for (int j = 0; j < 16; ++j)
    t[(size_t)(n0 + j) * CH] = (_Float16)(acc[j] + v);
}

// lrelu(s+d) . w over 8 channels, f32 accumulate via v_dot2_f32_f16
__device__ inline float edge_acc8(h8 s, h8 d, h8 w) {
  h8 t = s + d;                                  // 4x v_pk_add_f16
  h8 p = t * (_Float16)0.01f;                    // 4x v_pk_mul_f16
  h8 u = __builtin_elementwise_max(t, p);        // 4x v_pk_max_f16 (leaky relu)
  float acc = 0.f;
  acc = __builtin_amdgcn_fdot2(H2_OF(u, 0), H2_OF(w, 0), acc, false);
  acc = __builtin_amdgcn_fdot2(H2_OF(u, 1), H2_OF(w, 1), acc, false);
  acc = __builtin_amdgcn_fdot2(H2_OF(u, 2), H2_OF(w, 2), acc, false);
  acc = __builtin_amdgcn_fdot2(H2_OF(u, 3), H2_OF(w, 3), acc, false);
  return acc;
}

// K3: out[e] = b2 + sum_c w2[c] * lrelu(S[src[e]][c] + D[dst[e]][c])
// 16 lanes per edge-QUAD slot, 8 channels per lane, 4 edges per thread.
// 8 row-gathers in flight per thread (~60 VGPR -> 8 waves/SIMD); packed
// butterfly reduction (8 shfl + 3 selects for 4 edges); lanes 0-3 store.
// (EP=8 regressed: VGPR ~104 halves occupancy. Split-pass regressed: extra
// dispatch + index/partial round-trip. This EP=4 single-pass is the best
// measured config — bound by per-lane VMEM address throughput.)
__global__ __launch_bounds__(256) void k3_edges(
    const int* __restrict__ src, const int* __restrict__ dst,
    const _Float16* __restrict__ S, const _Float16* __restrict__ D,
    const _Float16* __restrict__ w2h, const float* __restrict__ b2,
    float* __restrict__ out) {
  int tid = blockIdx.x * 256 + threadIdx.x;
  int g = tid >> 4;             // edge-quad id, 0..N_EDGES/4-1
  int sub = tid & 15;
  int c0 = sub << 3;            // 8 channels per lane

  h8 w = *(const h8*)(w2h + c0);
  int4 s4 = *(const int4*)(src + 4 * g);   // broadcast across the 16 lanes
  int4 d4 = *(const int4*)(dst + 4 * g);

  const _Float16* Sp = S + c0;
  const _Float16* Dp = D + c0;
  h8 sr0 = *(const h8*)(Sp + ((size_t)s4.x << 7));
  h8 dr0 = *(const h8*)(Dp + ((size_t)d4.x << 7));
  h8 sr1 = *(const h8*)(Sp + ((size_t)s4.y << 7));
  h8 dr1 = *(const h8*)(Dp + ((size_t)d4.y << 7));
  h8 sr2 = *(const h8*)(Sp + ((size_t)s4.z << 7));
  h8 dr2 = *(const h8*)(Dp + ((size_t)d4.z << 7));
  h8 sr3 = *(const h8*)(Sp + ((size_t)s4.w << 7));
  h8 dr3 = *(const h8*)(Dp + ((size_t)d4.w << 7));

  float a0 = edge_acc8(sr0, dr0, w);
  float a1 = edge_acc8(sr1, dr1, w);
  float a2 = edge_acc8(sr2, dr2, w);
  float a3 = edge_acc8(sr3, dr3, w);

  // packed butterfly: after this, lane (sub&3)==k holds sum of edge k
  float r0 = a0 + __shfl_xor(a0, 1);
  float r1 = a1 + __shfl_xor(a1, 1);
  float r2 = a2 + __shfl_xor(a2, 1);
  float r3 = a3 + __shfl_xor(a3, 1);
  float v1 = (sub & 1) ? r1 : r0;
  float v2 = (sub & 1) ? r3 : r2;
  float t1 = v1 + __shfl_xor(v1, 2);
  float t2 = v2 + __shfl_xor(v2, 2);
  float u = (sub & 2) ? t2 : t1;
  u += __shfl_xor(u, 4);
  u += __shfl_xor(u, 8);

  if (sub < 4) out[4 * g + sub] = u + b2[0];
}

extern "C" void kernel_launch(void* const* d_in, const int* in_sizes, int n_in,
                              void* d_out, int out_size, void* d_ws, size_t ws_size,
                              hipStream_t stream) {
  const float* nf  = (const float*)d_in[0];
  // d_in[1] edge_feat, d_in[6] W_edge, d_in[7] b_edge: unused by the output
  const int*   src = (const int*)d_in[2];
  const int*   dst = (const int*)d_in[3];
  const float* Wn  = (const float*)d_in[4];
  const float* bn  = (const float*)d_in[5];
  const float* Wa1 = (const float*)d_in[8];
  const float* ba1 = (const float*)d_in[9];
  const float* Wa2 = (const float*)d_in[10];
  const float* ba2 = (const float*)d_in[11];
  float* out = (float*)d_out;

  char* ws = (char*)d_ws;
  float* M = (float*)ws;                                   // [2][118][128] f32
  float* V = (float*)(ws + 2 * KN * CH * sizeof(float));   // [2][128] f32
  _Float16* w2h = (_Float16*)(ws + (2 * KN * CH + 2 * CH) * sizeof(float));
  _Float16* T = (_Float16*)((char*)w2h + CH * sizeof(_Float16));
  _Float16* S = T;                                         // [10000][128] f16
  _Float16* D = T + (size_t)N_NODES * CH;                  // [10000][128] f16

  k1_weights<<<239, 128, 0, stream>>>(Wn, bn, Wa1, ba1, Wa2, M, V, w2h);
  k2_nodes<<<N_NODES / 16, 256, 0, stream>>>(nf, M, V, T);
  k3_edges<<<(N_EDGES / 4 * 16) / 256, 256, 0, stream>>>(src, dst, S, D, w2h, ba2, out);
}

// Round 8
// 145.787 us; speedup vs baseline: 1.1667x; 1.1447x over previous
//
#include <hip/hip_runtime.h>
#include <hip/hip_bf16.h>

#define N_NODES 10000
#define N_EDGES 640000
#define CH 128
#define KN 118   // node_feat inner dim

typedef _Float16 h2 __attribute__((ext_vector_type(2)));
typedef _Float16 h8 __attribute__((ext_vector_type(8)));
typedef float f32x4 __attribute__((ext_vector_type(4)));

#define H2_OF(v, k) __builtin_shufflevector((v), (v), 2 * (k), 2 * (k) + 1)

// K1: fold weights, TRANSPOSED + padded for the MFMA k2:
//   Mt[cg][k] = f16( sum_j Wn[k][j] * Wa1[mat*128 + j][c] ),  cg = mat*128+c,
//   k in [0,118); Mt[cg][118..127] = 0.
//   V[cg] = bn . Wa1col  (+ ba1[c] for mat==1), f32.
// Extra block (mat==2): w2 -> f16, and zero-pad Mt's k=118..127 columns.
__global__ __launch_bounds__(128) void k1_weights(
    const float* __restrict__ Wn, const float* __restrict__ bn,
    const float* __restrict__ Wa1, const float* __restrict__ ba1,
    const float* __restrict__ w2, _Float16* __restrict__ Mt,
    float* __restrict__ V, _Float16* __restrict__ w2h) {
  int c = threadIdx.x;                 // 0..127
  int mat = blockIdx.x / 119;          // 0: src-half, 1: dst-half, 2: misc
  int i = blockIdx.x % 119;            // 0..117 weight rows, 118 = bias row
  if (mat == 2) {
    w2h[c] = (_Float16)w2[c];
#pragma unroll
    for (int cg = c; cg < 256; cg += 128)
#pragma unroll
      for (int p = 118; p < 128; ++p) Mt[cg * 128 + p] = (_Float16)0.f;
    return;
  }
  const float* B = Wa1 + mat * CH * CH;
  const float* a = (i < KN) ? (Wn + i * CH) : bn;
  float acc = 0.f;
#pragma unroll 8
  for (int j = 0; j < CH; ++j) acc = fmaf(a[j], B[j * CH + c], acc);
  int cg = mat * CH + c;
  if (i < KN) {
    Mt[cg * 128 + i] = (_Float16)acc;  // transposed: [col][k]
  } else {
    if (mat == 1) acc += ba1[c];
    V[cg] = acc;
  }
}

// K2 (MFMA): T[mat][n][c] = f16( nf[n][:] . M[:][cg] + V[cg] )
// 128 threads = 2 waves; 32 nodes per block; each wave: 16 nodes x 256 cols
// via 16 col-tiles x 4 K-steps of mfma_f32_16x16x32_f16. Mt (64 KB f16)
// staged in LDS with an XOR-8 k-swizzle (kills the stride-256B bank clash).
// Fragment layouts (verified): A[m=lane&15][k=quad*8+j], B[n=lane&15][k=...],
// C/D: col=lane&15, row=quad*4+reg.
__global__ __launch_bounds__(128) void k2_mfma(
    const float* __restrict__ nf, const _Float16* __restrict__ Mt,
    const float* __restrict__ V, _Float16* __restrict__ T) {
  __shared__ _Float16 Blds[256 * 128];   // 64 KB
  int tx = threadIdx.x;

  // Stage Mt -> LDS in 16B chunks, applying the k-swizzle:
  // element (cg,k) lives at Blds[cg*128 + (k ^ ((cg&7)*8))].
#pragma unroll
  for (int it = 0; it < 32; ++it) {
    int chunk = it * 128 + tx;          // 0..4095 chunks of 8 f16
    int cg = chunk >> 4;
    int k0 = (chunk & 15) << 3;
    h8 v = *(const h8*)(Mt + cg * 128 + k0);
    *(h8*)(Blds + cg * 128 + (k0 ^ ((cg & 7) << 3))) = v;
  }

  int wave = tx >> 6;
  int lane = tx & 63;
  int m = lane & 15;                    // node within wave tile / col within ct
  int quad = lane >> 4;
  int nbase = blockIdx.x * 32 + wave * 16;
  int node = nbase + m;
  const float* arow = nf + (size_t)(node < N_NODES ? node : 0) * KN;

  h8 afrag[4];
#pragma unroll
  for (int s = 0; s < 4; ++s) {
#pragma unroll
    for (int j = 0; j < 8; ++j) {
      int k = s * 32 + quad * 8 + j;
      afrag[s][j] = (k < KN) ? (_Float16)arow[k] : (_Float16)0.f;
    }
  }
  __syncthreads();

  f32x4 acc[16];
#pragma unroll
  for (int ct = 0; ct < 16; ++ct) acc[ct] = f32x4{0.f, 0.f, 0.f, 0.f};
  int swz = (m & 7) << 3;               // cg&7 == n&7 within a col-tile
#pragma unroll
  for (int ct = 0; ct < 16; ++ct) {
    const _Float16* brow = Blds + (ct * 16 + m) * 128;
#pragma unroll
    for (int s = 0; s < 4; ++s) {
      h8 b = *(const h8*)(brow + ((s * 32 + quad * 8) ^ swz));
      acc[ct] = __builtin_amdgcn_mfma_f32_16x16x32_f16(afrag[s], b, acc[ct], 0, 0, 0);
    }
  }

  // Epilogue: bias in f32, convert to f16, store.
#pragma unroll
  for (int ct = 0; ct < 16; ++ct) {
    int cg = ct * 16 + m;
    float bias = V[cg];
    int mat = cg >> 7;
    int cc = cg & (CH - 1);
    int nd0 = nbase + quad * 4;
    _Float16* tp = T + ((size_t)mat * N_NODES + nd0) * CH + cc;
#pragma unroll
    for (int r = 0; r < 4; ++r) {
      if (nd0 + r < N_NODES) tp[(size_t)r * CH] = (_Float16)(acc[ct][r] + bias);
    }
  }
}

// lrelu(s+d) . w over 8 channels, f32 accumulate via v_dot2_f32_f16
__device__ inline float edge_acc8(h8 s, h8 d, h8 w) {
  h8 t = s + d;                                  // 4x v_pk_add_f16
  h8 p = t * (_Float16)0.01f;                    // 4x v_pk_mul_f16
  h8 u = __builtin_elementwise_max(t, p);        // 4x v_pk_max_f16 (leaky relu)
  float acc = 0.f;
  acc = __builtin_amdgcn_fdot2(H2_OF(u, 0), H2_OF(w, 0), acc, false);
  acc = __builtin_amdgcn_fdot2(H2_OF(u, 1), H2_OF(w, 1), acc, false);
  acc = __builtin_amdgcn_fdot2(H2_OF(u, 2), H2_OF(w, 2), acc, false);
  acc = __builtin_amdgcn_fdot2(H2_OF(u, 3), H2_OF(w, 3), acc, false);
  return acc;
}

// K3: out[e] = b2 + sum_c w2[c] * lrelu(S[src[e]][c] + D[dst[e]][c])
// 16 lanes per edge-QUAD slot, 8 channels per lane, 4 edges per thread.
// (EP=8 regressed: VGPR ~104 halves occupancy. Split-pass regressed: extra
// dispatch + index/partial round-trip. This EP=4 single-pass is the best
// measured config — bound by per-lane VMEM/gather throughput.)
__global__ __launch_bounds__(256) void k3_edges(
    const int* __restrict__ src, const int* __restrict__ dst,
    const _Float16* __restrict__ S, const _Float16* __restrict__ D,
    const _Float16* __restrict__ w2h, const float* __restrict__ b2,
    float* __restrict__ out) {
  int tid = blockIdx.x * 256 + threadIdx.x;
  int g = tid >> 4;             // edge-quad id, 0..N_EDGES/4-1
  int sub = tid & 15;
  int c0 = sub << 3;            // 8 channels per lane

  h8 w = *(const h8*)(w2h + c0);
  int4 s4 = *(const int4*)(src + 4 * g);   // broadcast across the 16 lanes
  int4 d4 = *(const int4*)(dst + 4 * g);

  const _Float16* Sp = S + c0;
  const _Float16* Dp = D + c0;
  h8 sr0 = *(const h8*)(Sp + ((size_t)s4.x << 7));
  h8 dr0 = *(const h8*)(Dp + ((size_t)d4.x << 7));
  h8 sr1 = *(const h8*)(Sp + ((size_t)s4.y << 7));
  h8 dr1 = *(const h8*)(Dp + ((size_t)d4.y << 7));
  h8 sr2 = *(const h8*)(Sp + ((size_t)s4.z << 7));
  h8 dr2 = *(const h8*)(Dp + ((size_t)d4.z << 7));
  h8 sr3 = *(const h8*)(Sp + ((size_t)s4.w << 7));
  h8 dr3 = *(const h8*)(Dp + ((size_t)d4.w << 7));

  float a0 = edge_acc8(sr0, dr0, w);
  float a1 = edge_acc8(sr1, dr1, w);
  float a2 = edge_acc8(sr2, dr2, w);
  float a3 = edge_acc8(sr3, dr3, w);

  // packed butterfly: after this, lane (sub&3)==k holds sum of edge k
  float r0 = a0 + __shfl_xor(a0, 1);
  float r1 = a1 + __shfl_xor(a1, 1);
  float r2 = a2 + __shfl_xor(a2, 1);
  float r3 = a3 + __shfl_xor(a3, 1);
  float v1 = (sub & 1) ? r1 : r0;
  float v2 = (sub & 1) ? r3 : r2;
  float t1 = v1 + __shfl_xor(v1, 2);
  float t2 = v2 + __shfl_xor(v2, 2);
  float u = (sub & 2) ? t2 : t1;
  u += __shfl_xor(u, 4);
  u += __shfl_xor(u, 8);

  if (sub < 4) out[4 * g + sub] = u + b2[0];
}

extern "C" void kernel_launch(void* const* d_in, const int* in_sizes, int n_in,
                              void* d_out, int out_size, void* d_ws, size_t ws_size,
                              hipStream_t stream) {
  const float* nf  = (const float*)d_in[0];
  // d_in[1] edge_feat, d_in[6] W_edge, d_in[7] b_edge: unused by the output
  const int*   src = (const int*)d_in[2];
  const int*   dst = (const int*)d_in[3];
  const float* Wn  = (const float*)d_in[4];
  const float* bn  = (const float*)d_in[5];
  const float* Wa1 = (const float*)d_in[8];
  const float* ba1 = (const float*)d_in[9];
  const float* Wa2 = (const float*)d_in[10];
  const float* ba2 = (const float*)d_in[11];
  float* out = (float*)d_out;

  char* ws = (char*)d_ws;
  _Float16* Mt  = (_Float16*)ws;                            // [256][128] f16
  float*    V   = (float*)(ws + 256 * 128 * sizeof(_Float16));   // [256] f32
  _Float16* w2h = (_Float16*)((char*)V + 256 * sizeof(float));   // [128] f16
  _Float16* T   = (_Float16*)((char*)w2h + 128 * sizeof(_Float16));
  _Float16* S = T;                                         // [10000][128] f16
  _Float16* D = T + (size_t)N_NODES * CH;                  // [10000][128] f16

  k1_weights<<<239, 128, 0, stream>>>(Wn, bn, Wa1, ba1, Wa2, Mt, V, w2h);
  k2_mfma<<<(N_NODES + 31) / 32, 128, 0, stream>>>(nf, Mt, V, T);
  k3_edges<<<(N_EDGES / 4 * 16) / 256, 256, 0, stream>>>(src, dst, S, D, w2h, ba2, out);
}